// Round 6
// baseline (464.067 us; speedup 1.0000x reference)
//
#include <hip/hip_runtime.h>
#include <hip/hip_bf16.h>
#include <math.h>

#define NN 50000
#define NP 50048          // padded to 128-multiple for MFMA tiles
#define EE 800000
#define EPAD 1150016      // padded CSR capacity: E + 7*N, rounded up
#define DIN 128
#define HID 256
#define NCLS 16
#define NPROT 512

typedef __attribute__((ext_vector_type(8))) short short8;
typedef __attribute__((ext_vector_type(4))) float f32x4;

__device__ inline unsigned short f2b(float f) {
    union { float f; unsigned u; } c; c.f = f;
    unsigned u = c.u;
    unsigned r = (u + 0x7FFFu + ((u >> 16) & 1u)) >> 16;
    return (unsigned short)r;
}
__device__ inline float b2f(unsigned short u) {
    union { unsigned u; float f; } c; c.u = ((unsigned)u) << 16; return c.f;
}

// async global->LDS, 16B per lane; LDS dest must be wave-uniform base + lane*16,
// global SOURCE is per-lane (the gather trick).
#define GL2LDS16(g, l)                                                              \
    __builtin_amdgcn_global_load_lds(                                               \
        (const __attribute__((address_space(1))) unsigned int*)(g),                 \
        (__attribute__((address_space(3))) unsigned int*)(l), 16, 0, 0)

// ---------------- degree / CSR construction (node segments padded to x8) ----------------

__global__ __launch_bounds__(256) void k_count(const int* __restrict__ dst, int* __restrict__ cnt, int e) {
    int i = blockIdx.x * 256 + threadIdx.x;
    if (i < e) atomicAdd(&cnt[dst[i]], 1);
}

// block-local inclusive scan over PADDED counts; also emits dis = rsqrt(deg+1)
__global__ __launch_bounds__(256) void k_scan1(const int* __restrict__ cnt, int* __restrict__ excl,
                                               int* __restrict__ bsum, float* __restrict__ dis, int n) {
    __shared__ int s[256];
    int t = threadIdx.x;
    int i = blockIdx.x * 256 + t;
    int v = (i < n) ? cnt[i] : 0;
    if (i < n) dis[i] = rsqrtf((float)v + 1.0f);
    int vp = (v + 7) & ~7;          // pad each node's segment to a multiple of 8
    s[t] = vp; __syncthreads();
    for (int d = 1; d < 256; d <<= 1) {
        int add = (t >= d) ? s[t - d] : 0;
        __syncthreads();
        s[t] += add;
        __syncthreads();
    }
    if (i < n) excl[i] = s[t] - vp;
    if (t == 255) bsum[blockIdx.x] = s[255];
}

__global__ __launch_bounds__(256) void k_scan2(const int* __restrict__ bsum, int* __restrict__ boff, int nb) {
    __shared__ int s[256];
    int t = threadIdx.x;
    int v = (t < nb) ? bsum[t] : 0;
    s[t] = v; __syncthreads();
    for (int d = 1; d < 256; d <<= 1) {
        int add = (t >= d) ? s[t - d] : 0;
        __syncthreads();
        s[t] += add;
        __syncthreads();
    }
    if (t < nb) boff[t] = s[t] - v;
}

__global__ __launch_bounds__(256) void k_scan3(const int* __restrict__ excl, const int* __restrict__ boff,
                                               const int* __restrict__ bsum,
                                               int* __restrict__ off, int n, int nb) {
    int i = blockIdx.x * 256 + threadIdx.x;
    if (i < n) off[i] = excl[i] + boff[blockIdx.x];
    if (i == 0) off[n] = boff[nb - 1] + bsum[nb - 1];   // total padded count
}

__global__ __launch_bounds__(256) void k_fill(const int* __restrict__ src, const int* __restrict__ dst,
                                              const int* __restrict__ off, int* __restrict__ cursor,
                                              const float* __restrict__ dis,
                                              int2* __restrict__ csr_e, int e) {
    int i = blockIdx.x * 256 + threadIdx.x;
    if (i >= e) return;
    int s = src[i], d = dst[i];
    int pos = atomicAdd(&cursor[d], 1);
    csr_e[off[d] + pos] = make_int2(s, __float_as_int(dis[s] * dis[d]));
}

// ---------------- fused prep: cast x -> bf16, transpose W0/W1 -> bf16 [n][k] ----------------

#define CAST_BLKS (NN * DIN / 4 / 256)   // 6250
#define WT0_BLKS  (DIN * HID / 256)      // 128
#define WT1_BLKS  (HID * HID / 256)      // 256

__global__ __launch_bounds__(256) void k_prep(const float* __restrict__ x, unsigned short* __restrict__ xb,
                                              const float* __restrict__ W0, unsigned short* __restrict__ Wt0,
                                              const float* __restrict__ W1, unsigned short* __restrict__ Wt1) {
    int b = blockIdx.x, t = threadIdx.x;
    if (b < CAST_BLKS) {
        int i = b * 256 + t;
        float4 v = ((const float4*)x)[i];
        ushort4 o; o.x = f2b(v.x); o.y = f2b(v.y); o.z = f2b(v.z); o.w = f2b(v.w);
        ((ushort4*)xb)[i] = o;
    } else if (b < CAST_BLKS + WT0_BLKS) {
        int i = (b - CAST_BLKS) * 256 + t;
        int k = i / HID, n = i - k * HID;
        Wt0[n * DIN + k] = f2b(W0[(size_t)k * HID + n]);
    } else {
        int i = (b - CAST_BLKS - WT0_BLKS) * 256 + t;
        int k = i / HID, n = i - k * HID;
        Wt1[n * HID + k] = f2b(W1[(size_t)k * HID + n]);
    }
}

// ---------------- bf16 MFMA GEMM: C[M,Nc] = A[Mp,K] @ Bt[Nc,K]^T ----------------
// mode 0: plain bf16 store (unguarded).  mode 2: +bias[col], relu, bf16 store (unguarded).

__global__ __launch_bounds__(256) void k_gemm_mfma(const unsigned short* __restrict__ A,
                                                   const unsigned short* __restrict__ Bt,
                                                   void* __restrict__ C, int M, int Nc, int K, int mode,
                                                   const float* __restrict__ bias) {
    __shared__ __align__(16) unsigned short As[128 * 32];  // 8 KB, unpadded (global_load_lds layout)
    __shared__ __align__(16) unsigned short Bs[128 * 32];
    const int t = threadIdx.x;
    const int lane = t & 63;
    const int quad = lane >> 4;
    const int l16 = lane & 15;
    const int wv = t >> 6;
    const int wm = (wv & 1) * 64, wn = (wv >> 1) * 64;
    const int m0 = blockIdx.y * 128, n0 = blockIdx.x * 128;

    f32x4 acc[4][4];
#pragma unroll
    for (int i = 0; i < 4; ++i)
#pragma unroll
        for (int j = 0; j < 4; ++j)
#pragma unroll
            for (int r = 0; r < 4; ++r) acc[i][j][r] = 0.0f;

    const int sr = t >> 2;         // staging row 0..63 (per half)
    const int sc = (t & 3) * 8;    // short offset in row: 0,8,16,24

    for (int k0 = 0; k0 < K; k0 += 32) {
        GL2LDS16(A + (size_t)(m0 + sr) * K + k0 + sc,       &As[t * 8]);
        GL2LDS16(A + (size_t)(m0 + 64 + sr) * K + k0 + sc,  &As[2048 + t * 8]);
        GL2LDS16(Bt + (size_t)(n0 + sr) * K + k0 + sc,      &Bs[t * 8]);
        GL2LDS16(Bt + (size_t)(n0 + 64 + sr) * K + k0 + sc, &Bs[2048 + t * 8]);
        __syncthreads();
        short8 af[4], bf[4];
#pragma unroll
        for (int i = 0; i < 4; ++i)
            af[i] = *(const short8*)&As[(wm + i * 16 + l16) * 32 + quad * 8];
#pragma unroll
        for (int j = 0; j < 4; ++j)
            bf[j] = *(const short8*)&Bs[(wn + j * 16 + l16) * 32 + quad * 8];
#pragma unroll
        for (int i = 0; i < 4; ++i)
#pragma unroll
            for (int j = 0; j < 4; ++j)
                acc[i][j] = __builtin_amdgcn_mfma_f32_16x16x32_bf16(af[i], bf[j], acc[i][j], 0, 0, 0);
        __syncthreads();
    }

#pragma unroll
    for (int i = 0; i < 4; ++i) {
        int rb = m0 + wm + i * 16 + quad * 4;
#pragma unroll
        for (int j = 0; j < 4; ++j) {
            int col = n0 + wn + j * 16 + l16;
#pragma unroll
            for (int rg = 0; rg < 4; ++rg) {
                int r = rb + rg;
                float v = acc[i][j][rg];
                if (mode == 0) {
                    ((unsigned short*)C)[(size_t)r * Nc + col] = f2b(v);
                } else {
                    v = fmaxf(v + bias[col], 0.0f);
                    ((unsigned short*)C)[(size_t)r * Nc + col] = f2b(v);
                }
            }
        }
    }
}

// ---------------- GCN aggregation (128-dim): async LDS-staged gather ----------------
// One wave per node. global_load_lds with PER-LANE source = async gather DMA:
// one instr = 4 rows (16 lanes x 16B each); up to 8 instrs (32 rows) in flight,
// ONE vmcnt(0) per 32 edges instead of one latency per edge (r5 lesson: VALU-expressed
// gathers get register-minimized to ~2 in flight regardless of launch_bounds).

__global__ __launch_bounds__(256) void k_agg128(const unsigned short* __restrict__ xw, const int* __restrict__ off,
                                                const int2* __restrict__ csr, const float* __restrict__ dis,
                                                unsigned short* __restrict__ out, int n) {
    __shared__ __align__(16) unsigned short rb[4 * 32 * 128];   // 4 waves x 32 rows x 256B = 32 KB
    int node = (blockIdx.x * 256 + threadIdx.x) >> 6;
    int lane = threadIdx.x & 63;
    unsigned short* mybuf = rb + (threadIdx.x >> 6) * (32 * 128);
    if (node >= n) return;
    float d = dis[node];
    float w0 = d * d;
    ushort2 u = ((const ushort2*)(xw + (size_t)node * DIN))[lane];
    float a0 = w0 * b2f(u.x), a1 = w0 * b2f(u.y);
    int p = off[node], p1 = off[node + 1];
    while (p < p1) {
        int seg = min(p1 - p, 64);                       // multiple of 8
        int2 di = csr[p + (lane < seg ? lane : seg - 1)];  // descriptors in lane regs
        for (int b = 0; b < seg; b += 32) {
            int nrows = min(32, seg - b);                // 8/16/24/32
            for (int s = 0; s < nrows; s += 4) {
                int e = b + s + ((lane >> 4) & 3);
                int srcn = __shfl(di.x, e, 64);
                GL2LDS16(xw + (size_t)srcn * DIN + (lane & 15) * 8, &mybuf[s * 128]);
            }
            asm volatile("s_waitcnt vmcnt(0)" ::: "memory");
            __builtin_amdgcn_sched_barrier(0);
            for (int k = 0; k < nrows; ++k) {
                float w = __int_as_float(__shfl(di.y, b + k, 64));
                ushort2 v = *(const ushort2*)&mybuf[k * 128 + lane * 2];
                a0 = fmaf(w, b2f(v.x), a0); a1 = fmaf(w, b2f(v.y), a1);
            }
            __builtin_amdgcn_sched_barrier(0);           // keep next issues after consume
        }
        p += seg;
    }
    ushort2 o; o.x = f2b(a0); o.y = f2b(a1);
    ((ushort2*)(out + (size_t)node * DIN))[lane] = o;
}

// ---------------- GCN aggregation (256-dim): async LDS-staged gather + normalize ----------------
// one instr = 2 rows (32 lanes x 16B each); up to 8 instrs (16 rows) in flight per wait.

__global__ __launch_bounds__(256) void k_agg256(const unsigned short* __restrict__ xw, const int* __restrict__ off,
                                                const int2* __restrict__ csr, const float* __restrict__ dis,
                                                const float* __restrict__ bias,
                                                unsigned short* __restrict__ out, float* __restrict__ nx, int n) {
    __shared__ __align__(16) unsigned short rb[4 * 16 * 256];   // 4 waves x 16 rows x 512B = 32 KB
    int node = (blockIdx.x * 256 + threadIdx.x) >> 6;
    int lane = threadIdx.x & 63;
    unsigned short* mybuf = rb + (threadIdx.x >> 6) * (16 * 256);
    if (node >= n) return;
    float d = dis[node];
    float w0 = d * d;
    ushort4 u = ((const ushort4*)(xw + (size_t)node * HID))[lane];
    float a0 = w0 * b2f(u.x), a1 = w0 * b2f(u.y), a2 = w0 * b2f(u.z), a3 = w0 * b2f(u.w);
    int p = off[node], p1 = off[node + 1];
    while (p < p1) {
        int seg = min(p1 - p, 64);                       // multiple of 8
        int2 di = csr[p + (lane < seg ? lane : seg - 1)];
        for (int b = 0; b < seg; b += 16) {
            int nrows = min(16, seg - b);                // 8 or 16
            for (int s = 0; s < nrows; s += 2) {
                int e = b + s + (lane >> 5);
                int srcn = __shfl(di.x, e, 64);
                GL2LDS16(xw + (size_t)srcn * HID + (lane & 31) * 8, &mybuf[s * 256]);
            }
            asm volatile("s_waitcnt vmcnt(0)" ::: "memory");
            __builtin_amdgcn_sched_barrier(0);
            for (int k = 0; k < nrows; ++k) {
                float w = __int_as_float(__shfl(di.y, b + k, 64));
                ushort4 v = *(const ushort4*)&mybuf[k * 256 + lane * 4];
                a0 = fmaf(w, b2f(v.x), a0); a1 = fmaf(w, b2f(v.y), a1);
                a2 = fmaf(w, b2f(v.z), a2); a3 = fmaf(w, b2f(v.w), a3);
            }
            __builtin_amdgcn_sched_barrier(0);
        }
        p += seg;
    }
    float4 b = ((const float4*)bias)[lane];
    a0 += b.x; a1 += b.y; a2 += b.z; a3 += b.w;
    // fused L2 row-normalize (reference: h /= ||h||, nx = ||h_normed|| recomputed)
    float ss = a0 * a0 + a1 * a1 + a2 * a2 + a3 * a3;
    for (int m = 32; m >= 1; m >>= 1) ss += __shfl_xor(ss, m, 64);
    float qn = sqrtf(ss);
    a0 /= qn; a1 /= qn; a2 /= qn; a3 /= qn;
    float s2 = a0 * a0 + a1 * a1 + a2 * a2 + a3 * a3;
    for (int m = 32; m >= 1; m >>= 1) s2 += __shfl_xor(s2, m, 64);
    if (lane == 0) nx[node] = sqrtf(s2);
    ushort4 o; o.x = f2b(a0); o.y = f2b(a1); o.z = f2b(a2); o.w = f2b(a3);
    ((ushort4*)(out + (size_t)node * HID))[lane] = o;
}

// ---------------- fused anchor gather + prototype head ----------------
// block = one anchor: stage h[prot[b]] row, emit aRb (bf16 for xrel GEMM) + na, then MLP + log_softmax.

__global__ __launch_bounds__(256) void k_gproto(const unsigned short* __restrict__ hb,
                                                const int* __restrict__ prot, const float* __restrict__ nx,
                                                unsigned short* __restrict__ aRb, float* __restrict__ na,
                                                const float* __restrict__ Wl1, const float* __restrict__ bl1,
                                                const float* __restrict__ Wl2, const float* __restrict__ bl2,
                                                float* __restrict__ outp) {
    __shared__ float sa[HID];
    __shared__ float st[HID];
    int row = blockIdx.x, t = threadIdx.x;
    int p = prot[row];
    unsigned short us = hb[(size_t)p * HID + t];
    aRb[(size_t)row * HID + t] = us;
    sa[t] = b2f(us);
    if (t == 0) na[row] = nx[p];
    __syncthreads();
    float acc = bl1[t];
#pragma unroll 8
    for (int k = 0; k < HID; ++k) acc = fmaf(sa[k], Wl1[k * HID + t], acc);
    st[t] = fmaxf(acc, 0.0f);
    __syncthreads();
    if (t < 64) {
        int c = t & 15, ch = t >> 4;
        float z = 0.f;
#pragma unroll 8
        for (int k = ch * 64; k < ch * 64 + 64; ++k) z = fmaf(st[k], Wl2[k * NCLS + c], z);
        z += __shfl_xor(z, 16, 64);
        z += __shfl_xor(z, 32, 64);
        z += bl2[c];
        float m = z;
        for (int d = 8; d >= 1; d >>= 1) m = fmaxf(m, __shfl_xor(m, d, 64));
        float e = expf(z - m);
        float s = e;
        for (int d = 8; d >= 1; d >>= 1) s += __shfl_xor(s, d, 64);
        if (t < 16) outp[row * NCLS + c] = z - m - logf(s);
    }
}

// ---------------- fused x_rel + partial final head ----------------
// LDS OVERLAY: Xs (32 KB) reuses As+Bs (16 KB, dead after the K-loop's final barrier).
// Total 36.3 KB -> 4 blocks/CU (was 52.25 KB / 3 blocks; r5 occupancy 24.7% was the limiter).
// smem_us layout (shorts): As [0..4095] | Bs [4096..8191]   (phase 1)
//                          Xs [0..16383] | pTc [16384..18559] (phase 2)

#define XSW(row, cs) (((cs) ^ (((row) & 7) << 3)))
#define NWGX (4 * (NP / 128))   // 1564

__global__ __launch_bounds__(256, 4) void k_xrel_out(const unsigned short* __restrict__ A,
                                                     const unsigned short* __restrict__ Bt,
                                                     const float* __restrict__ nx, const float* __restrict__ na,
                                                     const float* __restrict__ proto,
                                                     float* __restrict__ xrel, float* __restrict__ opart) {
    __shared__ __align__(16) unsigned short smem_us[18560];   // 36.3 KB

    // bijective XCD swizzle (m204): contiguous work ranges per XCD, work = m-major, chunk-minor
    const int bid = blockIdx.x;
    const int q = NWGX / 8, r = NWGX % 8;      // 195, 4
    const int xcd = bid & 7, li = bid >> 3;
    const int wk = (xcd < r ? xcd * (q + 1) : r * (q + 1) + (xcd - r) * q) + li;
    const int m0 = (wk >> 2) * 128;
    const int nc = wk & 3;
    const int n0 = nc * 128;

    const int t = threadIdx.x;
    const int lane = t & 63;
    const int quad = lane >> 4;
    const int l16 = lane & 15;
    const int wv = t >> 6;
    const int wm = (wv & 1) * 64, wn = (wv >> 1) * 64;

    // preload nx for this block's 16 row positions
    float nxv[4][4];
#pragma unroll
    for (int i = 0; i < 4; ++i)
#pragma unroll
        for (int rg = 0; rg < 4; ++rg) {
            int rr = m0 + wm + i * 16 + quad * 4 + rg;
            nxv[i][rg] = nx[rr < NN ? rr : NN - 1];
        }
    float nav[4];
#pragma unroll
    for (int j = 0; j < 4; ++j) nav[j] = na[n0 + wn + j * 16 + l16];

    const int sr = t >> 2;
    const int sc = (t & 3) * 8;

    f32x4 acc[4][4];
#pragma unroll
    for (int i = 0; i < 4; ++i)
#pragma unroll
        for (int j = 0; j < 4; ++j)
#pragma unroll
            for (int rr = 0; rr < 4; ++rr) acc[i][j][rr] = 0.0f;

    for (int k0 = 0; k0 < HID; k0 += 32) {
        GL2LDS16(A + (size_t)(m0 + sr) * HID + k0 + sc,        &smem_us[t * 8]);
        GL2LDS16(A + (size_t)(m0 + 64 + sr) * HID + k0 + sc,   &smem_us[2048 + t * 8]);
        GL2LDS16(Bt + (size_t)(n0 + sr) * HID + k0 + sc,       &smem_us[4096 + t * 8]);
        GL2LDS16(Bt + (size_t)(n0 + 64 + sr) * HID + k0 + sc,  &smem_us[4096 + 2048 + t * 8]);
        __syncthreads();
        short8 af[4], bf[4];
#pragma unroll
        for (int i = 0; i < 4; ++i)
            af[i] = *(const short8*)&smem_us[(wm + i * 16 + l16) * 32 + quad * 8];
#pragma unroll
        for (int j = 0; j < 4; ++j)
            bf[j] = *(const short8*)&smem_us[4096 + (wn + j * 16 + l16) * 32 + quad * 8];
#pragma unroll
        for (int i = 0; i < 4; ++i)
#pragma unroll
            for (int j = 0; j < 4; ++j)
                acc[i][j] = __builtin_amdgcn_mfma_f32_16x16x32_bf16(af[i], bf[j], acc[i][j], 0, 0, 0);
        __syncthreads();
    }
    // After the final barrier all waves are done reading As/Bs -> safe to overlay Xs.

    // stage protoT slice for this chunk: pTc[c][kk] = bf16(proto[n0+kk][c])
    for (int i = t; i < 128 * NCLS; i += 256) {
        int kk = i >> 4, c = i & 15;
        smem_us[16384 + c * 136 + kk] = f2b(proto[(n0 + kk) * NCLS + c]);
    }

    // cosine-scale (v_rcp) and stage bf16 tile into XOR-swizzled Xs
#pragma unroll
    for (int i = 0; i < 4; ++i) {
#pragma unroll
        for (int j = 0; j < 4; ++j) {
            int cl = wn + j * 16 + l16;
#pragma unroll
            for (int rg = 0; rg < 4; ++rg) {
                int row = wm + i * 16 + quad * 4 + rg;
                float s = fmaxf(nxv[i][rg] * nav[j], 1e-6f);
                float v = acc[i][j][rg] * __builtin_amdgcn_rcpf(s);
                smem_us[row * 128 + XSW(row, cl)] = f2b(v);
            }
        }
    }
    __syncthreads();

    // (a) partial out: wave wv owns local rows wv*32 .. wv*32+31; k = this chunk's 128 cols
    f32x4 oacc[2];
#pragma unroll
    for (int rr = 0; rr < 4; ++rr) { oacc[0][rr] = 0.0f; oacc[1][rr] = 0.0f; }
#pragma unroll
    for (int ii = 0; ii < 2; ++ii) {
        int rbr = wv * 32 + ii * 16;
#pragma unroll
        for (int ks = 0; ks < 4; ++ks) {
            int row = rbr + l16;
            short8 af = *(const short8*)&smem_us[row * 128 + XSW(row, ks * 32 + quad * 8)];
            short8 pb = *(const short8*)&smem_us[16384 + l16 * 136 + ks * 32 + quad * 8];
            oacc[ii] = __builtin_amdgcn_mfma_f32_16x16x32_bf16(af, pb, oacc[ii], 0, 0, 0);
        }
    }
#pragma unroll
    for (int ii = 0; ii < 2; ++ii)
#pragma unroll
        for (int rg = 0; rg < 4; ++rg) {
            int lrow = wv * 32 + ii * 16 + quad * 4 + rg;
            opart[((size_t)nc * NP + m0 + lrow) * NCLS + l16] = oacc[ii][rg];
        }

    // (b) coalesced x_rel stores: bf16 -> fp32 expand, 16 lanes cover 512 B of one row
#pragma unroll
    for (int it = 0; it < 8; ++it) {
        int idx = it * 256 + t;          // 0..2047
        int row = idx >> 4;              // 0..127
        int c8 = (idx & 15) * 8;         // 0,8,..,120
        int rr = m0 + row;
        if (rr < NN) {
            short8 u = *(const short8*)&smem_us[row * 128 + XSW(row, c8)];
            float* dst = &xrel[(size_t)rr * NPROT + n0 + c8];
            float4 v0, v1;
            v0.x = b2f((unsigned short)u[0]); v0.y = b2f((unsigned short)u[1]);
            v0.z = b2f((unsigned short)u[2]); v0.w = b2f((unsigned short)u[3]);
            v1.x = b2f((unsigned short)u[4]); v1.y = b2f((unsigned short)u[5]);
            v1.z = b2f((unsigned short)u[6]); v1.w = b2f((unsigned short)u[7]);
            *(float4*)dst = v0;
            *(float4*)(dst + 4) = v1;
        }
    }
}

// ---------------- final reduce: out = log_softmax(sum of 4 chunk partials) ----------------

__global__ __launch_bounds__(256) void k_reduce(const float* __restrict__ opart, float* __restrict__ out) {
    int i = blockIdx.x * 256 + threadIdx.x;   // over NP*16
    int row = i >> 4, c = i & 15;
    float z = opart[i] + opart[(size_t)NP * NCLS + i] + opart[(size_t)2 * NP * NCLS + i] +
              opart[(size_t)3 * NP * NCLS + i];
    float mx = z;
    for (int d = 8; d >= 1; d >>= 1) mx = fmaxf(mx, __shfl_xor(mx, d, 64));
    float e = expf(z - mx);
    float s = e;
    for (int d = 8; d >= 1; d >>= 1) s += __shfl_xor(s, d, 64);
    if (row < NN) out[(size_t)row * NCLS + c] = z - mx - logf(s);
}

// ---------------- launch ----------------

extern "C" void kernel_launch(void* const* d_in, const int* in_sizes, int n_in,
                              void* d_out, int out_size, void* d_ws, size_t ws_size,
                              hipStream_t stream) {
    const float* x    = (const float*)d_in[0];
    const int*   eidx = (const int*)d_in[1];
    const int*   prot = (const int*)d_in[2];
    const float* W0  = (const float*)d_in[4];
    const float* b0  = (const float*)d_in[5];
    const float* W1  = (const float*)d_in[6];
    const float* b1  = (const float*)d_in[7];
    const float* Wl1 = (const float*)d_in[8];
    const float* bl1 = (const float*)d_in[9];
    const float* Wl2 = (const float*)d_in[10];
    const float* bl2 = (const float*)d_in[11];

    const int N = NN, E = EE;
    const int* esrc_in = eidx;
    const int* edst_in = eidx + E;

    // d_out layout: out [N,16] | x_rel [N,512] | out_proto [512,16]
    float* out_final = (float*)d_out;
    float* x_rel     = (float*)d_out + (size_t)N * NCLS;
    float* out_proto = x_rel + (size_t)N * NPROT;

    char* w = (char*)d_ws;
    auto alloc = [&](size_t bytes) { char* p = w; w += (bytes + 255) & ~(size_t)255; return p; };
    int*   cnt      = (int*)alloc((size_t)N * 4);
    int*   cursor   = (int*)alloc((size_t)N * 4);
    float* dis      = (float*)alloc((size_t)N * 4);
    int*   excl     = (int*)alloc((size_t)N * 4);
    int*   csr_off  = (int*)alloc((size_t)(N + 1) * 4);
    int*   bsum     = (int*)alloc(1024);
    int*   boff     = (int*)alloc(1024);
    int2*  csr_e    = (int2*)alloc((size_t)EPAD * 8);                       // padded CSR, 9.2 MB
    float* nx       = (float*)alloc((size_t)N * 4);
    float* na       = (float*)alloc((size_t)NPROT * 4);
    float* opart    = (float*)alloc((size_t)4 * NP * NCLS * 4);             // 12.8 MB
    unsigned short* xb    = (unsigned short*)alloc((size_t)NP * DIN * 2);   // 12.8 MB
    unsigned short* Wt0   = (unsigned short*)alloc((size_t)HID * DIN * 2);
    unsigned short* Wt1   = (unsigned short*)alloc((size_t)HID * HID * 2);
    unsigned short* bufAb = (unsigned short*)alloc((size_t)NP * HID * 2);   // 25.6 MB
    unsigned short* h0b   = (unsigned short*)alloc((size_t)NP * HID * 2);   // 25.6 MB
    unsigned short* aRb   = (unsigned short*)alloc((size_t)NPROT * HID * 2);
    unsigned short* a1 = bufAb;  // agg(x) [NP,128] bf16 — dead before G2 overwrites bufAb
    unsigned short* hb = h0b;    // normalized h — h0b dead once G2 has consumed it

    hipMemsetAsync(cnt, 0, (size_t)N * 4, stream);
    hipMemsetAsync(cursor, 0, (size_t)N * 4, stream);
    hipMemsetAsync(csr_e, 0, (size_t)EPAD * 8, stream);   // pad entries = {src=0, w=0.0}

    // CSR build (node segments padded to x8 => 64B-aligned, no tail in agg loops)
    k_count<<<(E + 255) / 256, 256, 0, stream>>>(edst_in, cnt, E);
    int NB = (N + 255) / 256;
    k_scan1<<<NB, 256, 0, stream>>>(cnt, excl, bsum, dis, N);
    k_scan2<<<1, 256, 0, stream>>>(bsum, boff, NB);
    k_scan3<<<NB, 256, 0, stream>>>(excl, boff, bsum, csr_off, N, NB);
    k_fill<<<(E + 255) / 256, 256, 0, stream>>>(esrc_in, edst_in, csr_off, cursor, dis, csr_e, E);

    // prep: cast x, transpose weights (one fused launch)
    k_prep<<<CAST_BLKS + WT0_BLKS + WT1_BLKS, 256, 0, stream>>>(x, xb, W0, Wt0, W1, Wt1);

    const int MT = NP / 128;  // 391

    // layer 1 (flipped): a1 = agg(x);  h0 = relu(a1@W0 + b0)
    k_agg128<<<(N + 3) / 4, 256, 0, stream>>>(xb, csr_off, csr_e, dis, a1, N);
    k_gemm_mfma<<<dim3(HID / 128, MT), 256, 0, stream>>>(a1, Wt0, h0b, N, HID, DIN, 2, b0);

    // layer 2: h = normalize(agg(h0@W1) + b1)   (norm fused into agg epilogue)
    k_gemm_mfma<<<dim3(HID / 128, MT), 256, 0, stream>>>(h0b, Wt1, bufAb, N, HID, HID, 0, nullptr);
    k_agg256<<<(N + 3) / 4, 256, 0, stream>>>(bufAb, csr_off, csr_e, dis, b1, hb, nx, N);

    // anchors + prototype head (fused)
    k_gproto<<<NPROT, 256, 0, stream>>>(hb, prot, nx, aRb, na, Wl1, bl1, Wl2, bl2, out_proto);

    // fused: x_rel = (h @ anchors^T)/max(nx*na,eps)  AND  partial out = x_rel @ out_proto
    k_xrel_out<<<NWGX, 256, 0, stream>>>(hb, aRb, nx, na, out_proto, x_rel, opart);

    // out = log_softmax(sum of partials)
    k_reduce<<<NP * NCLS / 256, 256, 0, stream>>>(opart, out_final);
}

// Round 8
// 434.580 us; speedup vs baseline: 1.0679x; 1.0679x over previous
//
#include <hip/hip_runtime.h>
#include <hip/hip_bf16.h>
#include <math.h>

#define NN 50000
#define NP 50048          // padded to 128-multiple for MFMA tiles
#define EE 800000
#define EPAD 1150016      // padded CSR capacity: E + 7*N, rounded up
#define DIN 128
#define HID 256
#define NCLS 16
#define NPROT 512

typedef __attribute__((ext_vector_type(8))) short short8;
typedef __attribute__((ext_vector_type(4))) float f32x4;
typedef unsigned int u32;
typedef unsigned long long u64;

__device__ inline unsigned short f2b(float f) {
    union { float f; unsigned u; } c; c.f = f;
    unsigned u = c.u;
    unsigned r = (u + 0x7FFFu + ((u >> 16) & 1u)) >> 16;
    return (unsigned short)r;
}
__device__ inline float b2f(unsigned short u) {
    union { unsigned u; float f; } c; c.u = ((unsigned)u) << 16; return c.f;
}

// async global->LDS, 16B per lane; LDS dest must be wave-uniform base + lane*16
#define GL2LDS16(g, l)                                                              \
    __builtin_amdgcn_global_load_lds(                                               \
        (const __attribute__((address_space(1))) unsigned int*)(g),                 \
        (__attribute__((address_space(3))) unsigned int*)(l), 16, 0, 0)

// ---------------- degree / CSR construction (node segments padded to x8) ----------------

__global__ __launch_bounds__(256) void k_count(const int* __restrict__ dst, int* __restrict__ cnt, int e) {
    int i = blockIdx.x * 256 + threadIdx.x;
    if (i < e) atomicAdd(&cnt[dst[i]], 1);
}

// block-local inclusive scan over PADDED counts; also emits dis = rsqrt(deg+1)
__global__ __launch_bounds__(256) void k_scan1(const int* __restrict__ cnt, int* __restrict__ excl,
                                               int* __restrict__ bsum, float* __restrict__ dis, int n) {
    __shared__ int s[256];
    int t = threadIdx.x;
    int i = blockIdx.x * 256 + t;
    int v = (i < n) ? cnt[i] : 0;
    if (i < n) dis[i] = rsqrtf((float)v + 1.0f);
    int vp = (v + 7) & ~7;          // pad each node's segment to a multiple of 8
    s[t] = vp; __syncthreads();
    for (int d = 1; d < 256; d <<= 1) {
        int add = (t >= d) ? s[t - d] : 0;
        __syncthreads();
        s[t] += add;
        __syncthreads();
    }
    if (i < n) excl[i] = s[t] - vp;
    if (t == 255) bsum[blockIdx.x] = s[255];
}

__global__ __launch_bounds__(256) void k_scan2(const int* __restrict__ bsum, int* __restrict__ boff, int nb) {
    __shared__ int s[256];
    int t = threadIdx.x;
    int v = (t < nb) ? bsum[t] : 0;
    s[t] = v; __syncthreads();
    for (int d = 1; d < 256; d <<= 1) {
        int add = (t >= d) ? s[t - d] : 0;
        __syncthreads();
        s[t] += add;
        __syncthreads();
    }
    if (t < nb) boff[t] = s[t] - v;
}

__global__ __launch_bounds__(256) void k_scan3(const int* __restrict__ excl, const int* __restrict__ boff,
                                               const int* __restrict__ bsum,
                                               int* __restrict__ off, int n, int nb) {
    int i = blockIdx.x * 256 + threadIdx.x;
    if (i < n) off[i] = excl[i] + boff[blockIdx.x];
    if (i == 0) off[n] = boff[nb - 1] + bsum[nb - 1];   // total padded count
}

__global__ __launch_bounds__(256) void k_fill(const int* __restrict__ src, const int* __restrict__ dst,
                                              const int* __restrict__ off, int* __restrict__ cursor,
                                              const float* __restrict__ dis,
                                              int2* __restrict__ csr_e, int e) {
    int i = blockIdx.x * 256 + threadIdx.x;
    if (i >= e) return;
    int s = src[i], d = dst[i];
    int pos = atomicAdd(&cursor[d], 1);
    csr_e[off[d] + pos] = make_int2(s, __float_as_int(dis[s] * dis[d]));
}

// ---------------- fused prep: cast x -> bf16, transpose W0/W1 -> bf16 [n][k] ----------------

#define CAST_BLKS (NN * DIN / 4 / 256)   // 6250
#define WT0_BLKS  (DIN * HID / 256)      // 128
#define WT1_BLKS  (HID * HID / 256)      // 256

__global__ __launch_bounds__(256) void k_prep(const float* __restrict__ x, unsigned short* __restrict__ xb,
                                              const float* __restrict__ W0, unsigned short* __restrict__ Wt0,
                                              const float* __restrict__ W1, unsigned short* __restrict__ Wt1) {
    int b = blockIdx.x, t = threadIdx.x;
    if (b < CAST_BLKS) {
        int i = b * 256 + t;
        float4 v = ((const float4*)x)[i];
        ushort4 o; o.x = f2b(v.x); o.y = f2b(v.y); o.z = f2b(v.z); o.w = f2b(v.w);
        ((ushort4*)xb)[i] = o;
    } else if (b < CAST_BLKS + WT0_BLKS) {
        int i = (b - CAST_BLKS) * 256 + t;
        int k = i / HID, n = i - k * HID;
        Wt0[n * DIN + k] = f2b(W0[(size_t)k * HID + n]);
    } else {
        int i = (b - CAST_BLKS - WT0_BLKS) * 256 + t;
        int k = i / HID, n = i - k * HID;
        Wt1[n * HID + k] = f2b(W1[(size_t)k * HID + n]);
    }
}

// ---------------- bf16 MFMA GEMM: C[M,Nc] = A[Mp,K] @ Bt[Nc,K]^T ----------------
// mode 0: plain bf16 store (unguarded).  mode 2: +bias[col], relu, bf16 store (unguarded).

__global__ __launch_bounds__(256) void k_gemm_mfma(const unsigned short* __restrict__ A,
                                                   const unsigned short* __restrict__ Bt,
                                                   void* __restrict__ C, int M, int Nc, int K, int mode,
                                                   const float* __restrict__ bias) {
    __shared__ __align__(16) unsigned short As[128 * 32];  // 8 KB, unpadded (global_load_lds layout)
    __shared__ __align__(16) unsigned short Bs[128 * 32];
    const int t = threadIdx.x;
    const int lane = t & 63;
    const int quad = lane >> 4;
    const int l16 = lane & 15;
    const int wv = t >> 6;
    const int wm = (wv & 1) * 64, wn = (wv >> 1) * 64;
    const int m0 = blockIdx.y * 128, n0 = blockIdx.x * 128;

    f32x4 acc[4][4];
#pragma unroll
    for (int i = 0; i < 4; ++i)
#pragma unroll
        for (int j = 0; j < 4; ++j)
#pragma unroll
            for (int r = 0; r < 4; ++r) acc[i][j][r] = 0.0f;

    const int sr = t >> 2;         // staging row 0..63 (per half)
    const int sc = (t & 3) * 8;    // short offset in row: 0,8,16,24

    for (int k0 = 0; k0 < K; k0 += 32) {
        GL2LDS16(A + (size_t)(m0 + sr) * K + k0 + sc,       &As[t * 8]);
        GL2LDS16(A + (size_t)(m0 + 64 + sr) * K + k0 + sc,  &As[2048 + t * 8]);
        GL2LDS16(Bt + (size_t)(n0 + sr) * K + k0 + sc,      &Bs[t * 8]);
        GL2LDS16(Bt + (size_t)(n0 + 64 + sr) * K + k0 + sc, &Bs[2048 + t * 8]);
        __syncthreads();
        short8 af[4], bf[4];
#pragma unroll
        for (int i = 0; i < 4; ++i)
            af[i] = *(const short8*)&As[(wm + i * 16 + l16) * 32 + quad * 8];
#pragma unroll
        for (int j = 0; j < 4; ++j)
            bf[j] = *(const short8*)&Bs[(wn + j * 16 + l16) * 32 + quad * 8];
#pragma unroll
        for (int i = 0; i < 4; ++i)
#pragma unroll
            for (int j = 0; j < 4; ++j)
                acc[i][j] = __builtin_amdgcn_mfma_f32_16x16x32_bf16(af[i], bf[j], acc[i][j], 0, 0, 0);
        __syncthreads();
    }

#pragma unroll
    for (int i = 0; i < 4; ++i) {
        int rb = m0 + wm + i * 16 + quad * 4;
#pragma unroll
        for (int j = 0; j < 4; ++j) {
            int col = n0 + wn + j * 16 + l16;
#pragma unroll
            for (int rg = 0; rg < 4; ++rg) {
                int r = rb + rg;
                float v = acc[i][j][rg];
                if (mode == 0) {
                    ((unsigned short*)C)[(size_t)r * Nc + col] = f2b(v);
                } else {
                    v = fmaxf(v + bias[col], 0.0f);
                    ((unsigned short*)C)[(size_t)r * Nc + col] = f2b(v);
                }
            }
        }
    }
}

// ---------------- GCN aggregation: asm-forced 8-deep gather pipeline ----------------
// One wave per node, padded CSR (x8 segments). Descriptors: ONE vector load per <=64 edges,
// broadcast via readlane (uniform scalar). Row gathers: one asm block with 8 global_load
// using PER-LANE 64-bit VGPR addresses ("v" constraints only — no SGPR-uniformity proof
// needed, hardened vs r7) + one vmcnt(0) -> 8 loads architecturally in flight; the
// compiler cannot register-minimize them away (r3/r4/r5 lesson).

#define GATHER8_D(go, ga)                                                      \
    asm volatile(                                                              \
        "global_load_dword %0, %[g0], off\n\t"                                 \
        "global_load_dword %1, %[g1], off\n\t"                                 \
        "global_load_dword %2, %[g2], off\n\t"                                 \
        "global_load_dword %3, %[g3], off\n\t"                                 \
        "global_load_dword %4, %[g4], off\n\t"                                 \
        "global_load_dword %5, %[g5], off\n\t"                                 \
        "global_load_dword %6, %[g6], off\n\t"                                 \
        "global_load_dword %7, %[g7], off\n\t"                                 \
        "s_waitcnt vmcnt(0)"                                                   \
        : "=&v"(go[0]), "=&v"(go[1]), "=&v"(go[2]), "=&v"(go[3]),              \
          "=&v"(go[4]), "=&v"(go[5]), "=&v"(go[6]), "=&v"(go[7])               \
        : [g0]"v"(ga[0]), [g1]"v"(ga[1]), [g2]"v"(ga[2]), [g3]"v"(ga[3]),      \
          [g4]"v"(ga[4]), [g5]"v"(ga[5]), [g6]"v"(ga[6]), [g7]"v"(ga[7])       \
        : "memory")

#define GATHER8_D2(go, ga)                                                     \
    asm volatile(                                                              \
        "global_load_dwordx2 %0, %[g0], off\n\t"                               \
        "global_load_dwordx2 %1, %[g1], off\n\t"                               \
        "global_load_dwordx2 %2, %[g2], off\n\t"                               \
        "global_load_dwordx2 %3, %[g3], off\n\t"                               \
        "global_load_dwordx2 %4, %[g4], off\n\t"                               \
        "global_load_dwordx2 %5, %[g5], off\n\t"                               \
        "global_load_dwordx2 %6, %[g6], off\n\t"                               \
        "global_load_dwordx2 %7, %[g7], off\n\t"                               \
        "s_waitcnt vmcnt(0)"                                                   \
        : "=&v"(go[0]), "=&v"(go[1]), "=&v"(go[2]), "=&v"(go[3]),              \
          "=&v"(go[4]), "=&v"(go[5]), "=&v"(go[6]), "=&v"(go[7])               \
        : [g0]"v"(ga[0]), [g1]"v"(ga[1]), [g2]"v"(ga[2]), [g3]"v"(ga[3]),      \
          [g4]"v"(ga[4]), [g5]"v"(ga[5]), [g6]"v"(ga[6]), [g7]"v"(ga[7])       \
        : "memory")

__global__ __launch_bounds__(256) void k_agg128(const unsigned short* __restrict__ xw, const int* __restrict__ off,
                                                const int2* __restrict__ csr, const float* __restrict__ dis,
                                                unsigned short* __restrict__ out, int n) {
    int node = (blockIdx.x * 256 + threadIdx.x) >> 6;
    int lane = threadIdx.x & 63;
    if (node >= n) return;
    float d = dis[node];
    float w0 = d * d;
    ushort2 u = ((const ushort2*)(xw + (size_t)node * DIN))[lane];
    float a0 = w0 * b2f(u.x), a1 = w0 * b2f(u.y);
    int p = off[node], p1 = off[node + 1];
    u64 lbase = (u64)xw + (u64)((unsigned)lane * 4u);   // this lane's ushort2 in a 256B row
    while (p < p1) {
        int seg = min(p1 - p, 64);         // multiple of 8
        int2 di = csr[p + (lane < seg ? lane : 0)];
        for (int b = 0; b < seg; b += 8) {
            u64 ga[8];
            int wi[8];
#pragma unroll
            for (int k = 0; k < 8; ++k) {
                int srcn = __builtin_amdgcn_readlane(di.x, b + k);
                wi[k] = __builtin_amdgcn_readlane(di.y, b + k);
                ga[k] = lbase + (u64)((u32)srcn * (u32)(DIN * 2));
            }
            u32 go[8];
            GATHER8_D(go, ga);
#pragma unroll
            for (int k = 0; k < 8; ++k) {
                float w = __int_as_float(wi[k]);
                a0 = fmaf(w, b2f((unsigned short)go[k]), a0);
                a1 = fmaf(w, b2f((unsigned short)(go[k] >> 16)), a1);
            }
        }
        p += seg;
    }
    ushort2 o; o.x = f2b(a0); o.y = f2b(a1);
    ((ushort2*)(out + (size_t)node * DIN))[lane] = o;
}

__global__ __launch_bounds__(256) void k_agg256(const unsigned short* __restrict__ xw, const int* __restrict__ off,
                                                const int2* __restrict__ csr, const float* __restrict__ dis,
                                                const float* __restrict__ bias,
                                                unsigned short* __restrict__ out, float* __restrict__ nx, int n) {
    int node = (blockIdx.x * 256 + threadIdx.x) >> 6;
    int lane = threadIdx.x & 63;
    if (node >= n) return;
    float d = dis[node];
    float w0 = d * d;
    ushort4 u = ((const ushort4*)(xw + (size_t)node * HID))[lane];
    float a0 = w0 * b2f(u.x), a1 = w0 * b2f(u.y), a2 = w0 * b2f(u.z), a3 = w0 * b2f(u.w);
    int p = off[node], p1 = off[node + 1];
    u64 lbase = (u64)xw + (u64)((unsigned)lane * 8u);   // this lane's ushort4 in a 512B row
    while (p < p1) {
        int seg = min(p1 - p, 64);         // multiple of 8
        int2 di = csr[p + (lane < seg ? lane : 0)];
        for (int b = 0; b < seg; b += 8) {
            u64 ga[8];
            int wi[8];
#pragma unroll
            for (int k = 0; k < 8; ++k) {
                int srcn = __builtin_amdgcn_readlane(di.x, b + k);
                wi[k] = __builtin_amdgcn_readlane(di.y, b + k);
                ga[k] = lbase + (u64)((u32)srcn * (u32)(HID * 2));
            }
            u64 go[8];
            GATHER8_D2(go, ga);
#pragma unroll
            for (int k = 0; k < 8; ++k) {
                float w = __int_as_float(wi[k]);
                u32 lo = (u32)go[k], hi = (u32)(go[k] >> 32);
                a0 = fmaf(w, b2f((unsigned short)lo), a0);
                a1 = fmaf(w, b2f((unsigned short)(lo >> 16)), a1);
                a2 = fmaf(w, b2f((unsigned short)hi), a2);
                a3 = fmaf(w, b2f((unsigned short)(hi >> 16)), a3);
            }
        }
        p += seg;
    }
    float4 b = ((const float4*)bias)[lane];
    a0 += b.x; a1 += b.y; a2 += b.z; a3 += b.w;
    // fused L2 row-normalize (reference: h /= ||h||, nx = ||h_normed|| recomputed)
    float ss = a0 * a0 + a1 * a1 + a2 * a2 + a3 * a3;
    for (int m = 32; m >= 1; m >>= 1) ss += __shfl_xor(ss, m, 64);
    float qn = sqrtf(ss);
    a0 /= qn; a1 /= qn; a2 /= qn; a3 /= qn;
    float s2 = a0 * a0 + a1 * a1 + a2 * a2 + a3 * a3;
    for (int m = 32; m >= 1; m >>= 1) s2 += __shfl_xor(s2, m, 64);
    if (lane == 0) nx[node] = sqrtf(s2);
    ushort4 o; o.x = f2b(a0); o.y = f2b(a1); o.z = f2b(a2); o.w = f2b(a3);
    ((ushort4*)(out + (size_t)node * HID))[lane] = o;
}

// ---------------- fused anchor gather + prototype head ----------------
// block = one anchor: stage h[prot[b]] row, emit aRb (bf16 for xrel GEMM) + na, then MLP + log_softmax.

__global__ __launch_bounds__(256) void k_gproto(const unsigned short* __restrict__ hb,
                                                const int* __restrict__ prot, const float* __restrict__ nx,
                                                unsigned short* __restrict__ aRb, float* __restrict__ na,
                                                const float* __restrict__ Wl1, const float* __restrict__ bl1,
                                                const float* __restrict__ Wl2, const float* __restrict__ bl2,
                                                float* __restrict__ outp) {
    __shared__ float sa[HID];
    __shared__ float st[HID];
    int row = blockIdx.x, t = threadIdx.x;
    int p = prot[row];
    unsigned short us = hb[(size_t)p * HID + t];
    aRb[(size_t)row * HID + t] = us;
    sa[t] = b2f(us);
    if (t == 0) na[row] = nx[p];
    __syncthreads();
    float acc = bl1[t];
#pragma unroll 8
    for (int k = 0; k < HID; ++k) acc = fmaf(sa[k], Wl1[k * HID + t], acc);
    st[t] = fmaxf(acc, 0.0f);
    __syncthreads();
    if (t < 64) {
        int c = t & 15, ch = t >> 4;
        float z = 0.f;
#pragma unroll 8
        for (int k = ch * 64; k < ch * 64 + 64; ++k) z = fmaf(st[k], Wl2[k * NCLS + c], z);
        z += __shfl_xor(z, 16, 64);
        z += __shfl_xor(z, 32, 64);
        z += bl2[c];
        float m = z;
        for (int d = 8; d >= 1; d >>= 1) m = fmaxf(m, __shfl_xor(m, d, 64));
        float e = expf(z - m);
        float s = e;
        for (int d = 8; d >= 1; d >>= 1) s += __shfl_xor(s, d, 64);
        if (t < 16) outp[row * NCLS + c] = z - m - logf(s);
    }
}

// ---------------- fused x_rel + partial final head ----------------
// LDS OVERLAY: Xs (32 KB) reuses As+Bs (16 KB, dead after the K-loop's final barrier).
// Total 36.3 KB -> 4 blocks/CU. smem_us layout (shorts):
//   phase 1: As [0..4095] | Bs [4096..8191]
//   phase 2: Xs [0..16383] | pTc [16384..18559]

#define XSW(row, cs) (((cs) ^ (((row) & 7) << 3)))
#define NWGX (4 * (NP / 128))   // 1564

__global__ __launch_bounds__(256, 4) void k_xrel_out(const unsigned short* __restrict__ A,
                                                     const unsigned short* __restrict__ Bt,
                                                     const float* __restrict__ nx, const float* __restrict__ na,
                                                     const float* __restrict__ proto,
                                                     float* __restrict__ xrel, float* __restrict__ opart) {
    __shared__ __align__(16) unsigned short smem_us[18560];   // 36.3 KB

    // bijective XCD swizzle (m204): contiguous work ranges per XCD, work = m-major, chunk-minor
    const int bid = blockIdx.x;
    const int q = NWGX / 8, r = NWGX % 8;      // 195, 4
    const int xcd = bid & 7, li = bid >> 3;
    const int wk = (xcd < r ? xcd * (q + 1) : r * (q + 1) + (xcd - r) * q) + li;
    const int m0 = (wk >> 2) * 128;
    const int nc = wk & 3;
    const int n0 = nc * 128;

    const int t = threadIdx.x;
    const int lane = t & 63;
    const int quad = lane >> 4;
    const int l16 = lane & 15;
    const int wv = t >> 6;
    const int wm = (wv & 1) * 64, wn = (wv >> 1) * 64;

    // preload nx for this block's 16 row positions
    float nxv[4][4];
#pragma unroll
    for (int i = 0; i < 4; ++i)
#pragma unroll
        for (int rg = 0; rg < 4; ++rg) {
            int rr = m0 + wm + i * 16 + quad * 4 + rg;
            nxv[i][rg] = nx[rr < NN ? rr : NN - 1];
        }
    float nav[4];
#pragma unroll
    for (int j = 0; j < 4; ++j) nav[j] = na[n0 + wn + j * 16 + l16];

    const int sr = t >> 2;
    const int sc = (t & 3) * 8;

    f32x4 acc[4][4];
#pragma unroll
    for (int i = 0; i < 4; ++i)
#pragma unroll
        for (int j = 0; j < 4; ++j)
#pragma unroll
            for (int rr = 0; rr < 4; ++rr) acc[i][j][rr] = 0.0f;

    for (int k0 = 0; k0 < HID; k0 += 32) {
        GL2LDS16(A + (size_t)(m0 + sr) * HID + k0 + sc,        &smem_us[t * 8]);
        GL2LDS16(A + (size_t)(m0 + 64 + sr) * HID + k0 + sc,   &smem_us[2048 + t * 8]);
        GL2LDS16(Bt + (size_t)(n0 + sr) * HID + k0 + sc,       &smem_us[4096 + t * 8]);
        GL2LDS16(Bt + (size_t)(n0 + 64 + sr) * HID + k0 + sc,  &smem_us[4096 + 2048 + t * 8]);
        __syncthreads();
        short8 af[4], bf[4];
#pragma unroll
        for (int i = 0; i < 4; ++i)
            af[i] = *(const short8*)&smem_us[(wm + i * 16 + l16) * 32 + quad * 8];
#pragma unroll
        for (int j = 0; j < 4; ++j)
            bf[j] = *(const short8*)&smem_us[4096 + (wn + j * 16 + l16) * 32 + quad * 8];
#pragma unroll
        for (int i = 0; i < 4; ++i)
#pragma unroll
            for (int j = 0; j < 4; ++j)
                acc[i][j] = __builtin_amdgcn_mfma_f32_16x16x32_bf16(af[i], bf[j], acc[i][j], 0, 0, 0);
        __syncthreads();
    }
    // After the final barrier all waves are done reading As/Bs -> safe to overlay Xs.

    // stage protoT slice for this chunk: pTc[c][kk] = bf16(proto[n0+kk][c])
    for (int i = t; i < 128 * NCLS; i += 256) {
        int kk = i >> 4, c = i & 15;
        smem_us[16384 + c * 136 + kk] = f2b(proto[(n0 + kk) * NCLS + c]);
    }

    // cosine-scale (v_rcp) and stage bf16 tile into XOR-swizzled Xs
#pragma unroll
    for (int i = 0; i < 4; ++i) {
#pragma unroll
        for (int j = 0; j < 4; ++j) {
            int cl = wn + j * 16 + l16;
#pragma unroll
            for (int rg = 0; rg < 4; ++rg) {
                int row = wm + i * 16 + quad * 4 + rg;
                float s = fmaxf(nxv[i][rg] * nav[j], 1e-6f);
                float v = acc[i][j][rg] * __builtin_amdgcn_rcpf(s);
                smem_us[row * 128 + XSW(row, cl)] = f2b(v);
            }
        }
    }
    __syncthreads();

    // (a) partial out: wave wv owns local rows wv*32 .. wv*32+31; k = this chunk's 128 cols
    f32x4 oacc[2];
#pragma unroll
    for (int rr = 0; rr < 4; ++rr) { oacc[0][rr] = 0.0f; oacc[1][rr] = 0.0f; }
#pragma unroll
    for (int ii = 0; ii < 2; ++ii) {
        int rbr = wv * 32 + ii * 16;
#pragma unroll
        for (int ks = 0; ks < 4; ++ks) {
            int row = rbr + l16;
            short8 af = *(const short8*)&smem_us[row * 128 + XSW(row, ks * 32 + quad * 8)];
            short8 pb = *(const short8*)&smem_us[16384 + l16 * 136 + ks * 32 + quad * 8];
            oacc[ii] = __builtin_amdgcn_mfma_f32_16x16x32_bf16(af, pb, oacc[ii], 0, 0, 0);
        }
    }
#pragma unroll
    for (int ii = 0; ii < 2; ++ii)
#pragma unroll
        for (int rg = 0; rg < 4; ++rg) {
            int lrow = wv * 32 + ii * 16 + quad * 4 + rg;
            opart[((size_t)nc * NP + m0 + lrow) * NCLS + l16] = oacc[ii][rg];
        }

    // (b) coalesced x_rel stores: bf16 -> fp32 expand, 16 lanes cover 512 B of one row
#pragma unroll
    for (int it = 0; it < 8; ++it) {
        int idx = it * 256 + t;          // 0..2047
        int row = idx >> 4;              // 0..127
        int c8 = (idx & 15) * 8;         // 0,8,..,120
        int rr = m0 + row;
        if (rr < NN) {
            short8 u = *(const short8*)&smem_us[row * 128 + XSW(row, c8)];
            float* dst = &xrel[(size_t)rr * NPROT + n0 + c8];
            float4 v0, v1;
            v0.x = b2f((unsigned short)u[0]); v0.y = b2f((unsigned short)u[1]);
            v0.z = b2f((unsigned short)u[2]); v0.w = b2f((unsigned short)u[3]);
            v1.x = b2f((unsigned short)u[4]); v1.y = b2f((unsigned short)u[5]);
            v1.z = b2f((unsigned short)u[6]); v1.w = b2f((unsigned short)u[7]);
            *(float4*)dst = v0;
            *(float4*)(dst + 4) = v1;
        }
    }
}

// ---------------- final reduce: out = log_softmax(sum of 4 chunk partials) ----------------

__global__ __launch_bounds__(256) void k_reduce(const float* __restrict__ opart, float* __restrict__ out) {
    int i = blockIdx.x * 256 + threadIdx.x;   // over NP*16
    int row = i >> 4, c = i & 15;
    float z = opart[i] + opart[(size_t)NP * NCLS + i] + opart[(size_t)2 * NP * NCLS + i] +
              opart[(size_t)3 * NP * NCLS + i];
    float mx = z;
    for (int d = 8; d >= 1; d >>= 1) mx = fmaxf(mx, __shfl_xor(mx, d, 64));
    float e = expf(z - mx);
    float s = e;
    for (int d = 8; d >= 1; d >>= 1) s += __shfl_xor(s, d, 64);
    if (row < NN) out[(size_t)row * NCLS + c] = z - mx - logf(s);
}

// ---------------- launch ----------------

extern "C" void kernel_launch(void* const* d_in, const int* in_sizes, int n_in,
                              void* d_out, int out_size, void* d_ws, size_t ws_size,
                              hipStream_t stream) {
    const float* x    = (const float*)d_in[0];
    const int*   eidx = (const int*)d_in[1];
    const int*   prot = (const int*)d_in[2];
    const float* W0  = (const float*)d_in[4];
    const float* b0  = (const float*)d_in[5];
    const float* W1  = (const float*)d_in[6];
    const float* b1  = (const float*)d_in[7];
    const float* Wl1 = (const float*)d_in[8];
    const float* bl1 = (const float*)d_in[9];
    const float* Wl2 = (const float*)d_in[10];
    const float* bl2 = (const float*)d_in[11];

    const int N = NN, E = EE;
    const int* esrc_in = eidx;
    const int* edst_in = eidx + E;

    // d_out layout: out [N,16] | x_rel [N,512] | out_proto [512,16]
    float* out_final = (float*)d_out;
    float* x_rel     = (float*)d_out + (size_t)N * NCLS;
    float* out_proto = x_rel + (size_t)N * NPROT;

    char* w = (char*)d_ws;
    auto alloc = [&](size_t bytes) { char* p = w; w += (bytes + 255) & ~(size_t)255; return p; };
    int*   cnt      = (int*)alloc((size_t)N * 4);
    int*   cursor   = (int*)alloc((size_t)N * 4);
    float* dis      = (float*)alloc((size_t)N * 4);
    int*   excl     = (int*)alloc((size_t)N * 4);
    int*   csr_off  = (int*)alloc((size_t)(N + 1) * 4);
    int*   bsum     = (int*)alloc(1024);
    int*   boff     = (int*)alloc(1024);
    int2*  csr_e    = (int2*)alloc((size_t)EPAD * 8);                       // padded CSR, 9.2 MB
    float* nx       = (float*)alloc((size_t)N * 4);
    float* na       = (float*)alloc((size_t)NPROT * 4);
    float* opart    = (float*)alloc((size_t)4 * NP * NCLS * 4);             // 12.8 MB
    unsigned short* xb    = (unsigned short*)alloc((size_t)NP * DIN * 2);   // 12.8 MB
    unsigned short* Wt0   = (unsigned short*)alloc((size_t)HID * DIN * 2);
    unsigned short* Wt1   = (unsigned short*)alloc((size_t)HID * HID * 2);
    unsigned short* bufAb = (unsigned short*)alloc((size_t)NP * HID * 2);   // 25.6 MB
    unsigned short* h0b   = (unsigned short*)alloc((size_t)NP * HID * 2);   // 25.6 MB
    unsigned short* aRb   = (unsigned short*)alloc((size_t)NPROT * HID * 2);
    unsigned short* a1 = bufAb;  // agg(x) [NP,128] bf16 — dead before G2 overwrites bufAb
    unsigned short* hb = h0b;    // normalized h — h0b dead once G2 has consumed it

    hipMemsetAsync(cnt, 0, (size_t)N * 4, stream);
    hipMemsetAsync(cursor, 0, (size_t)N * 4, stream);
    hipMemsetAsync(csr_e, 0, (size_t)EPAD * 8, stream);   // pad entries = {src=0, w=0.0}

    // CSR build (node segments padded to x8 => 64B-aligned, no tail in agg loops)
    k_count<<<(E + 255) / 256, 256, 0, stream>>>(edst_in, cnt, E);
    int NB = (N + 255) / 256;
    k_scan1<<<NB, 256, 0, stream>>>(cnt, excl, bsum, dis, N);
    k_scan2<<<1, 256, 0, stream>>>(bsum, boff, NB);
    k_scan3<<<NB, 256, 0, stream>>>(excl, boff, bsum, csr_off, N, NB);
    k_fill<<<(E + 255) / 256, 256, 0, stream>>>(esrc_in, edst_in, csr_off, cursor, dis, csr_e, E);

    // prep: cast x, transpose weights (one fused launch)
    k_prep<<<CAST_BLKS + WT0_BLKS + WT1_BLKS, 256, 0, stream>>>(x, xb, W0, Wt0, W1, Wt1);

    const int MT = NP / 128;  // 391

    // layer 1 (flipped): a1 = agg(x);  h0 = relu(a1@W0 + b0)
    k_agg128<<<(N + 3) / 4, 256, 0, stream>>>(xb, csr_off, csr_e, dis, a1, N);
    k_gemm_mfma<<<dim3(HID / 128, MT), 256, 0, stream>>>(a1, Wt0, h0b, N, HID, DIN, 2, b0);

    // layer 2: h = normalize(agg(h0@W1) + b1)   (norm fused into agg epilogue)
    k_gemm_mfma<<<dim3(HID / 128, MT), 256, 0, stream>>>(h0b, Wt1, bufAb, N, HID, HID, 0, nullptr);
    k_agg256<<<(N + 3) / 4, 256, 0, stream>>>(bufAb, csr_off, csr_e, dis, b1, hb, nx, N);

    // anchors + prototype head (fused)
    k_gproto<<<NPROT, 256, 0, stream>>>(hb, prot, nx, aRb, na, Wl1, bl1, Wl2, bl2, out_proto);

    // fused: x_rel = (h @ anchors^T)/max(nx*na,eps)  AND  partial out = x_rel @ out_proto
    k_xrel_out<<<NWGX, 256, 0, stream>>>(hb, aRb, nx, na, out_proto, x_rel, opart);

    // out = log_softmax(sum of partials)
    k_reduce<<<NP * NCLS / 256, 256, 0, stream>>>(opart, out_final);
}